// Round 1
// baseline (361.173 us; speedup 1.0000x reference)
//
#include <hip/hip_runtime.h>

// ---------------------------------------------------------------------------
// HolographicMemory: out = softmax( x @ [Kr|Ki]^T * temp ) @ [Vr|Vi]
//   x: [32768, 1024] fp32, MEM=512, HEAD=512.
// Strategy: bf16 MFMA GEMMs (m97 structure), fused concat in packing.
// ---------------------------------------------------------------------------

#define DIMX   1024
#define MEMN   512
#define NROWS  32768
#define TEMP   0.04419417382415922f  // 512^-0.5

typedef __bf16 bf16;
typedef __bf16 bf16x8 __attribute__((ext_vector_type(8)));
typedef float  f32x4  __attribute__((ext_vector_type(4)));

// async global->LDS, 16B per lane; LDS dest is wave-uniform base + lane*16
__device__ __forceinline__ void gload_lds16(const void* g, void* l) {
    __builtin_amdgcn_global_load_lds(
        (const __attribute__((address_space(1))) unsigned*)g,
        (__attribute__((address_space(3))) unsigned*)l,
        16, 0, 0);
}

// ---------------- pack x (fp32 -> bf16), 8 elems/thread --------------------
__global__ __launch_bounds__(256) void pack_x_kernel(const float* __restrict__ x,
                                                     bf16* __restrict__ xb) {
    const int i = (blockIdx.x * 256 + threadIdx.x) * 8;
    f32x4 a = *(const f32x4*)(x + i);
    f32x4 b = *(const f32x4*)(x + i + 4);
    bf16x8 o;
    o[0] = (bf16)a[0]; o[1] = (bf16)a[1]; o[2] = (bf16)a[2]; o[3] = (bf16)a[3];
    o[4] = (bf16)b[0]; o[5] = (bf16)b[1]; o[6] = (bf16)b[2]; o[7] = (bf16)b[3];
    *(bf16x8*)(xb + i) = o;
}

// ------- pack K' = [Kr|Ki] as [512][1024]; V'^T as [1024][512] (bf16) ------
__global__ __launch_bounds__(256) void pack_kv_kernel(const float* __restrict__ kr,
                                                      const float* __restrict__ ki,
                                                      const float* __restrict__ vr,
                                                      const float* __restrict__ vi,
                                                      bf16* __restrict__ Kb,
                                                      bf16* __restrict__ VbT) {
    const int idx = blockIdx.x * 256 + threadIdx.x;   // 0 .. 512*1024-1
    {   // Kb[m][h'] : h'<512 -> Kr[m][h'], else Ki[m][h'-512]
        const int m = idx >> 10, h = idx & 1023;
        const float v = (h < 512) ? kr[m * 512 + h] : ki[m * 512 + (h - 512)];
        Kb[idx] = (bf16)v;
    }
    {   // VbT[h'][m] : h'<512 -> Vr[m][h'], else Vi[m][h'-512]
        const int hp = idx >> 9, m = idx & 511;
        const float v = (hp < 512) ? vr[m * 512 + hp] : vi[m * 512 + (hp - 512)];
        VbT[idx] = (bf16)v;
    }
}

// ---------------- m97-style GEMM: C[M,N] = A[M,K] * Bt[N,K]^T --------------
// 128x128 block tile, BK=32, 256 threads (4 waves, 2x2), 16x16x32 bf16 MFMA,
// global_load_lds width-16 staging. OUT_BF16: write bf16, else fp32.
template <bool OUT_BF16>
__global__ __launch_bounds__(256) void gemm_bt_kernel(const bf16* __restrict__ A,
                                                      const bf16* __restrict__ Bt,
                                                      void* __restrict__ Cv,
                                                      int M, int N, int K) {
    __shared__ bf16 As[128 * 32];
    __shared__ bf16 Bs[128 * 32];

    const int tid  = threadIdx.x;
    const int wave = tid >> 6, lane = tid & 63;
    const int rowB = blockIdx.y * 128;
    const int colB = blockIdx.x * 128;
    const int wrow = (wave >> 1) * 64;
    const int wcol = (wave & 1) * 64;
    const int lm   = lane & 15;         // row(A)/n(B)/col(C) within 16-tile
    const int lkb  = (lane >> 4) * 8;   // k base within 32-chunk

    // staging: thread t covers rows {t/4, t/4+64}, k-cols (t%4)*8..+7
    const int srow  = tid >> 2;
    const int skcol = (tid & 3) * 8;

    const bf16* Ab = A  + (size_t)rowB * K;
    const bf16* Bb = Bt + (size_t)colB * K;

    f32x4 acc[4][4] = {};

    for (int k0 = 0; k0 < K; k0 += 32) {
        __syncthreads();   // previous iter's ds_reads done before overwrite
        gload_lds16(Ab + (size_t)srow * K + k0 + skcol,        As + wave * 512);
        gload_lds16(Ab + (size_t)(srow + 64) * K + k0 + skcol, As + 2048 + wave * 512);
        gload_lds16(Bb + (size_t)srow * K + k0 + skcol,        Bs + wave * 512);
        gload_lds16(Bb + (size_t)(srow + 64) * K + k0 + skcol, Bs + 2048 + wave * 512);
        __syncthreads();   // emits s_waitcnt vmcnt(0) + barrier

        bf16x8 af[4], bfr[4];
        #pragma unroll
        for (int i = 0; i < 4; ++i)
            af[i] = *(const bf16x8*)(As + (wrow + i * 16 + lm) * 32 + lkb);
        #pragma unroll
        for (int j = 0; j < 4; ++j)
            bfr[j] = *(const bf16x8*)(Bs + (wcol + j * 16 + lm) * 32 + lkb);

        #pragma unroll
        for (int i = 0; i < 4; ++i)
            #pragma unroll
            for (int j = 0; j < 4; ++j)
                acc[i][j] = __builtin_amdgcn_mfma_f32_16x16x32_bf16(
                    af[i], bfr[j], acc[i][j], 0, 0, 0);
    }

    // C/D layout: col = lane&15, row = (lane>>4)*4 + reg   [m89-verified]
    const int r0 = rowB + wrow + (lane >> 4) * 4;
    const int c0 = colB + wcol + lm;
    #pragma unroll
    for (int i = 0; i < 4; ++i) {
        #pragma unroll
        for (int j = 0; j < 4; ++j) {
            #pragma unroll
            for (int r = 0; r < 4; ++r) {
                const size_t off = (size_t)(r0 + i * 16 + r) * N + (c0 + j * 16);
                if (OUT_BF16) ((bf16*)Cv)[off]  = (bf16)acc[i][j][r];
                else          ((float*)Cv)[off] = acc[i][j][r];
            }
        }
    }
}

// ---------------- softmax over rows of 512 (in-place, bf16) ----------------
// one wave per row; lane holds 8 elems (16B vector load)
__global__ __launch_bounds__(256) void softmax_kernel(bf16* __restrict__ e) {
    const int wave = threadIdx.x >> 6, lane = threadIdx.x & 63;
    const size_t row = (size_t)blockIdx.x * 4 + wave;
    bf16* p = e + row * MEMN + lane * 8;
    bf16x8 v = *(const bf16x8*)p;

    float f[8];
    float mx = -1e30f;
    #pragma unroll
    for (int i = 0; i < 8; ++i) { f[i] = (float)v[i] * TEMP; mx = fmaxf(mx, f[i]); }
    #pragma unroll
    for (int off = 32; off > 0; off >>= 1) mx = fmaxf(mx, __shfl_xor(mx, off));

    float s = 0.f;
    #pragma unroll
    for (int i = 0; i < 8; ++i) { f[i] = __expf(f[i] - mx); s += f[i]; }
    #pragma unroll
    for (int off = 32; off > 0; off >>= 1) s += __shfl_xor(s, off);

    const float inv = 1.0f / s;
    bf16x8 o;
    #pragma unroll
    for (int i = 0; i < 8; ++i) o[i] = (bf16)(f[i] * inv);
    *(bf16x8*)p = o;
}

// ---------------------------------------------------------------------------
extern "C" void kernel_launch(void* const* d_in, const int* in_sizes, int n_in,
                              void* d_out, int out_size, void* d_ws, size_t ws_size,
                              hipStream_t stream) {
    const float* x  = (const float*)d_in[0];
    const float* kr = (const float*)d_in[1];
    const float* ki = (const float*)d_in[2];
    const float* vr = (const float*)d_in[3];
    const float* vi = (const float*)d_in[4];
    float* out = (float*)d_out;

    char* ws = (char*)d_ws;
    bf16* xb   = (bf16*)ws;                                   // 32768*1024*2 = 64 MiB
    bf16* Kb   = (bf16*)(ws + (size_t)67108864);              // 512*1024*2  =  1 MiB
    bf16* VbT  = (bf16*)(ws + (size_t)67108864 + 1048576);    // 1024*512*2  =  1 MiB
    bf16* attn = (bf16*)(ws + (size_t)67108864 + 2097152);    // 32768*512*2 = 32 MiB

    // 1) pack x -> bf16 (33554432 elems / 8 per thread / 256 per block)
    pack_x_kernel<<<16384, 256, 0, stream>>>(x, xb);
    // 2) pack K' and V'^T
    pack_kv_kernel<<<2048, 256, 0, stream>>>(kr, ki, vr, vi, Kb, VbT);
    // 3) energy = xb @ Kb^T  -> bf16 [32768, 512]
    gemm_bt_kernel<true><<<dim3(4, 256), 256, 0, stream>>>(xb, Kb, attn,
                                                           NROWS, MEMN, DIMX);
    // 4) softmax rows (temp folded in), in-place
    softmax_kernel<<<8192, 256, 0, stream>>>(attn);
    // 5) out = attn @ VbT^T -> fp32 [32768, 1024]
    gemm_bt_kernel<false><<<dim3(8, 256), 256, 0, stream>>>(attn, VbT, out,
                                                            NROWS, DIMX, MEMN);
}